// Round 3
// baseline (208.808 us; speedup 1.0000x reference)
//
#include <hip/hip_runtime.h>

typedef __attribute__((ext_vector_type(8))) short bf16x8;
typedef __attribute__((ext_vector_type(4))) float f32x4;
typedef __attribute__((ext_vector_type(8))) unsigned short u16x8;

#define DEVINL __device__ __forceinline__

constexpr int NI = 256;   // input channels (K)
constexpr int NO = 256;   // output channels
constexpr int NC = 120;   // irrep feature width
constexpr int KQ = 64;    // K staged per LDS fill
constexpr int NSTAGE = NI / KQ;   // 4
constexpr int CW = 8;     // c-tile width: 120 = 15 * 8, no tail

DEVINL ushort f2bf(float x) {   // round-to-nearest-even fp32 -> bf16 bits (inputs finite)
  unsigned u = __float_as_uint(x);
  u += 0x7FFFu + ((u >> 16) & 1u);
  return (ushort)(u >> 16);
}

// column c -> global weight-matrix id (0..55); monotone in c
constexpr int mat_of(int c) {
  return c < 32 ? c : (c < 80 ? 32 + (c - 32) / 3 : 48 + (c - 80) / 5);
}

// ---- prep: wb[((m*32 + k/8)*256 + o)*8 + k%8] = bf16(W_m[o][k]) ----
__global__ __launch_bounds__(256) void prep_w(const float* __restrict__ w0,
                                              const float* __restrict__ w1,
                                              const float* __restrict__ w2,
                                              ushort* __restrict__ wb) {
  const int m = blockIdx.x >> 5;        // 0..55
  const int kc = blockIdx.x & 31;       // k-chunk of 8
  const int o = threadIdx.x;            // 0..255
  const float* src;
  if (m < 32)      src = w0 + ((size_t)(m * NO + o)) * NI;
  else if (m < 48) src = w1 + ((size_t)((m - 32) * NO + o)) * NI;
  else             src = w2 + ((size_t)((m - 48) * NO + o)) * NI;
  src += kc * 8;
  float4 a = *reinterpret_cast<const float4*>(src);
  float4 b = *reinterpret_cast<const float4*>(src + 4);
  u16x8 p = { f2bf(a.x), f2bf(a.y), f2bf(a.z), f2bf(a.w),
              f2bf(b.x), f2bf(b.y), f2bf(b.z), f2bf(b.w) };
  *reinterpret_cast<u16x8*>(wb + ((size_t)(blockIdx.x * 256 + o)) * 8) = p;
}

// ---- main: block = 256 thr / 4 waves = [16 b] x [64 o] x [8 c], K in 4 stages via LDS ----
template<int CT>
DEVINL void tile_body(const float* __restrict__ x, const ushort* __restrict__ wb,
                      const float* __restrict__ bias0, float* __restrict__ out,
                      int bt, int oq, ushort* xs) {
  constexpr int c0 = CT * CW;
  constexpr int M0 = mat_of(c0);
  constexpr int NM = mat_of(c0 + CW - 1) - M0 + 1;   // 2..4, or 8 (group-0 tiles)
  constexpr int NCH = (NM > 4) ? 2 : 1;              // matrix chunks per stage
  constexpr int CPC = CW / NCH;                      // columns per chunk

  const int tid  = threadIdx.x;
  const int lane = tid & 63;
  const int wid  = tid >> 6;               // 4 waves, each owns 16 o-columns
  const int bg   = bt * 16;
  const int ocol = oq * 64 + wid * 16 + (lane & 15);

  const int rb = lane & 15;                // A-frag row (b)
  const int rg = lane >> 4;                // A/B-frag k-group

  // staging map: per thread 8 consecutive k x 4 c (one quad) at one b
  const int cq = tid & 1;                  // c-quad (0/1)
  const int sb = (tid >> 1) & 15;          // b row
  const int kb = tid >> 5;                 // k-block of 8 (0..7)

  f32x4 acc[CW];
#pragma unroll
  for (int i = 0; i < CW; ++i) acc[i] = (f32x4)0.0f;

#pragma unroll 1
  for (int s = 0; s < NSTAGE; ++s) {
    if (s) __syncthreads();                // all waves done reading xs before overwrite
    {
      const float* src = x + (size_t)(bg + sb) * (NI * NC)
                           + (size_t)(s * KQ + kb * 8) * NC + (c0 + 4 * cq);
      f32x4 v[8];
#pragma unroll
      for (int j = 0; j < 8; ++j) v[j] = *reinterpret_cast<const f32x4*>(src + j * NC);
#pragma unroll
      for (int c = 0; c < 4; ++c) {
        const int cc = 4 * cq + c;
        const int row = cc * 16 + sb;
        const int swz = ((sb & 7) ^ (cc & 7)) << 3;    // XOR bank swizzle on k
#pragma unroll
        for (int jq = 0; jq < 2; ++jq) {
          const int kpos = (kb * 8 + jq * 4) ^ swz;    // stays 4-aligned
          ushort4 p;
          p.x = f2bf(v[jq * 4 + 0][c]); p.y = f2bf(v[jq * 4 + 1][c]);
          p.z = f2bf(v[jq * 4 + 2][c]); p.w = f2bf(v[jq * 4 + 3][c]);
          *reinterpret_cast<ushort4*>(xs + row * KQ + kpos) = p;
        }
      }
    }
    __syncthreads();

#pragma unroll
    for (int ch = 0; ch < NCH; ++ch) {
      constexpr int MPC = (NCH == 2) ? 4 : NM;         // matrices preloaded this chunk
      bf16x8 w0r[MPC], w1r[MPC];
#pragma unroll
      for (int j = 0; j < MPC; ++j) {                  // preload -> pipelined L2 loads
        const int m = M0 + ch * 4 + j;
        const ushort* wp = wb + ((size_t)((m * 32 + s * 8 + rg) * NO + ocol)) * 8;
        w0r[j] = *reinterpret_cast<const bf16x8*>(wp);
        w1r[j] = *reinterpret_cast<const bf16x8*>(wp + (size_t)4 * NO * 8);
      }
#pragma unroll
      for (int cl = 0; cl < CPC; ++cl) {
        const int cc = ch * CPC + cl;
        const int j = mat_of(c0 + cc) - M0 - ch * 4;   // compile-time folded
        const ushort* xp = xs + (cc * 16 + rb) * KQ;
        const int swzr = ((rb & 7) ^ (cc & 7)) << 3;
        bf16x8 a0 = *reinterpret_cast<const bf16x8*>(xp + ((rg * 8) ^ swzr));
        acc[cc] = __builtin_amdgcn_mfma_f32_16x16x32_bf16(a0, w0r[j], acc[cc], 0, 0, 0);
        bf16x8 a1 = *reinterpret_cast<const bf16x8*>(xp + ((32 + rg * 8) ^ swzr));
        acc[cc] = __builtin_amdgcn_mfma_f32_16x16x32_bf16(a1, w1r[j], acc[cc], 0, 0, 0);
      }
    }
  }

  if (CT < 4) {                             // l=0 irreps (c<32): bias b0[m=c][o]
#pragma unroll
    for (int cc = 0; cc < CW; ++cc) {
      float bv = bias0[(c0 + cc) * NO + ocol];
      acc[cc] += bv;
    }
  }

  const int br0 = bg + rg * 4;              // D row = (lane>>4)*4 + reg
#pragma unroll
  for (int r = 0; r < 4; ++r) {
#pragma unroll
    for (int q = 0; q < CW / 4; ++q) {      // 2 x 16B stores, 32B contiguous
      float4 v = make_float4(acc[4 * q + 0][r], acc[4 * q + 1][r],
                             acc[4 * q + 2][r], acc[4 * q + 3][r]);
      float* dst = out + ((size_t)(br0 + r) * NO + ocol) * NC + (c0 + 4 * q);
      *reinterpret_cast<float4*>(dst) = v;
    }
  }
}

__global__ __launch_bounds__(256, 4) void e3mix(const float* __restrict__ x,
                                                const ushort* __restrict__ wb,
                                                const float* __restrict__ bias0,
                                                float* __restrict__ out) {
  __shared__ ushort xs[CW * 16 * KQ];       // 16 KB
  const int bid = blockIdx.x;
  const int ct = bid & 15;                  // fastest -> XCD-pinned W slice (~2 MB, L2-fit)
  const int oq = (bid >> 4) & 3;
  const int bt = bid >> 6;                  // slowest -> b-slice L3-shared across XCDs
  if (ct == 15) return;                     // 120 = 15 tiles of 8; slot 15 empty
  switch (ct) {
    case 0:  tile_body<0>(x, wb, bias0, out, bt, oq, xs); break;
    case 1:  tile_body<1 >(x, wb, bias0, out, bt, oq, xs); break;
    case 2:  tile_body<2 >(x, wb, bias0, out, bt, oq, xs); break;
    case 3:  tile_body<3 >(x, wb, bias0, out, bt, oq, xs); break;
    case 4:  tile_body<4 >(x, wb, bias0, out, bt, oq, xs); break;
    case 5:  tile_body<5 >(x, wb, bias0, out, bt, oq, xs); break;
    case 6:  tile_body<6 >(x, wb, bias0, out, bt, oq, xs); break;
    case 7:  tile_body<7 >(x, wb, bias0, out, bt, oq, xs); break;
    case 8:  tile_body<8 >(x, wb, bias0, out, bt, oq, xs); break;
    case 9:  tile_body<9 >(x, wb, bias0, out, bt, oq, xs); break;
    case 10: tile_body<10>(x, wb, bias0, out, bt, oq, xs); break;
    case 11: tile_body<11>(x, wb, bias0, out, bt, oq, xs); break;
    case 12: tile_body<12>(x, wb, bias0, out, bt, oq, xs); break;
    case 13: tile_body<13>(x, wb, bias0, out, bt, oq, xs); break;
    default: tile_body<14>(x, wb, bias0, out, bt, oq, xs); break;
  }
}

extern "C" void kernel_launch(void* const* d_in, const int* in_sizes, int n_in,
                              void* d_out, int out_size, void* d_ws, size_t ws_size,
                              hipStream_t stream) {
  const float* x  = (const float*)d_in[0];
  const float* w0 = (const float*)d_in[1];
  const float* w1 = (const float*)d_in[2];
  const float* w2 = (const float*)d_in[3];
  const float* b0 = (const float*)d_in[4];
  float* out = (float*)d_out;
  ushort* wb = (ushort*)d_ws;               // 7.34 MB of scratch

  prep_w<<<56 * 32, 256, 0, stream>>>(w0, w1, w2, wb);
  e3mix<<<16 * 4 * 64, 256, 0, stream>>>(x, wb, b0, out);
}